// Round 2
// baseline (407.656 us; speedup 1.0000x reference)
//
#include <hip/hip_runtime.h>
#include <hip/hip_cooperative_groups.h>

namespace cg = cooperative_groups;

#define BSZ   2
#define LSEQ  2048
#define DQ    512
#define SQ    4
#define EPSQ  1e-6f

typedef float nfloat4 __attribute__((ext_vector_type(4)));  // native vec for nontemporal
typedef float nfloat2 __attribute__((ext_vector_type(2)));  // VOP3P packed pair

__device__ __forceinline__ nfloat2 mk2(float x, float y) { nfloat2 v; v.x = x; v.y = y; return v; }

// ---------------- packed quaternion (pairs (r,i),(j,k); v_pk_fma_f32 path) ---
struct PQuat { nfloat2 ri, jk; };

__device__ __forceinline__ PQuat pq_of(const float4 v) {
    PQuat p; p.ri = mk2(v.x, v.y); p.jk = mk2(v.z, v.w); return p;
}
__device__ __forceinline__ float4 f4_of(const PQuat p) {
    return make_float4(p.ri.x, p.ri.y, p.jk.x, p.jk.y);
}

// o = a x b  (8 packed mul/fma vs 16 scalar)
__device__ __forceinline__ PQuat pqmul(const PQuat a, const PQuat b) {
    const float ar = a.ri.x, ai = a.ri.y, aj = a.jk.x, ak = a.jk.y;
    PQuat o;
    o.ri = ar*b.ri + ai*mk2(-b.ri.y,  b.ri.x)
         + aj*mk2(-b.jk.x,  b.jk.y) + ak*mk2(-b.jk.y, -b.jk.x);
    o.jk = ar*b.jk + ai*mk2(-b.jk.y,  b.jk.x)
         + aj*mk2( b.ri.x, -b.ri.y) + ak*mk2( b.ri.y,  b.ri.x);
    return o;
}

// o = a x b + c
__device__ __forceinline__ PQuat pqmuladd(const PQuat a, const PQuat b, const PQuat c) {
    const float ar = a.ri.x, ai = a.ri.y, aj = a.jk.x, ak = a.jk.y;
    PQuat o;
    o.ri = c.ri + ar*b.ri + ai*mk2(-b.ri.y,  b.ri.x)
         + aj*mk2(-b.jk.x,  b.jk.y) + ak*mk2(-b.jk.y, -b.jk.x);
    o.jk = c.jk + ar*b.jk + ai*mk2(-b.jk.y,  b.jk.x)
         + aj*mk2( b.ri.x, -b.ri.y) + ak*mk2( b.ri.y,  b.ri.x);
    return o;
}

// Precomputed per-(d,s) A-quaternion state (hA = 0.5*dt-free part).
struct HA { float r, i; nfloat2 jk; float p2, n2r; };

__device__ __forceinline__ HA load_hA(const float* __restrict__ Alog,
                                      const float* __restrict__ Ai,
                                      const float* __restrict__ Aj,
                                      const float* __restrict__ Ak, int idx) {
    HA h;
    h.r  = -0.5f * __expf(Alog[idx]);
    h.i  =  0.5f * Ai[idx];
    h.jk = mk2(0.5f * Aj[idx], 0.5f * Ak[idx]);
    h.p2 = h.r*h.r + h.i*h.i + h.jk.x*h.jk.x + h.jk.y*h.jk.y;
    h.n2r = -2.0f * h.r;
    return h;
}

// Cayley transition q and injection Bu (packed, strength-reduced).
__device__ __forceinline__ void cayley_pk(const float a, const float aa, const HA& hA,
                                          const PQuat B, const PQuat U,
                                          PQuat& q, PQuat& Bu) {
    const float dd = __builtin_fmaf(aa, hA.p2, __builtin_fmaf(a, hA.n2r, 1.0f + EPSQ));
    const float sv = __builtin_amdgcn_rcpf(dd);
    const float nr = __builtin_fmaf(-aa, hA.p2, 1.0f);   // 1 - |w|^2
    const float as = a * sv;
    const float s2a = as + as;                            // 2*a*s
    q.ri = mk2(nr * sv, s2a * hA.i);
    q.jk = s2a * hA.jk;
    PQuat cd;                                             // conj(den) = (1-wr, w_im)
    cd.ri = mk2(__builtin_fmaf(-a, hA.r, 1.0f), a * hA.i);
    cd.jk = a * hA.jk;
    const PQuat cb = pqmul(cd, B);
    PQuat dB; dB.ri = as * cb.ri; dB.jk = as * cb.jk;
    Bu = pqmul(dB, U);
}

// ---------------- scalar quat (scan path) -----------------------------------
struct Quat { float r, i, j, k; };
__device__ __forceinline__ Quat qmul(const Quat a, const Quat b) {
    Quat o;
    o.r = a.r*b.r - a.i*b.i - a.j*b.j - a.k*b.k;
    o.i = a.r*b.i + a.i*b.r + a.j*b.k - a.k*b.j;
    o.j = a.r*b.j - a.i*b.k + a.j*b.r + a.k*b.i;
    o.k = a.r*b.k + a.i*b.j - a.j*b.i + a.k*b.r;
    return o;
}
__device__ __forceinline__ Quat qmuladd(const Quat a, const Quat b, const Quat c) {
    Quat o;
    o.r = c.r + a.r*b.r - a.i*b.i - a.j*b.j - a.k*b.k;
    o.i = c.i + a.r*b.i + a.i*b.r + a.j*b.k - a.k*b.j;
    o.j = c.j + a.r*b.j - a.i*b.k + a.j*b.r + a.k*b.i;
    o.k = c.k + a.r*b.k + a.i*b.j - a.j*b.i + a.k*b.r;
    return o;
}
__device__ __forceinline__ Quat q_of(const float4 v) { return Quat{v.x, v.y, v.z, v.w}; }
__device__ __forceinline__ float4 f4s_of(const Quat q) { return make_float4(q.r, q.i, q.j, q.k); }

// ======================= FUSED cooperative kernel ============================
// One launch, 1024 blocks x 256 threads, co-resident (launch_bounds(256,4) =>
// VGPR<=128 => >=4 blocks/CU => 1024 fit on 256 CUs). Two grid.sync()s.
// Working set (~110 MB: u+dt+B+C+W+out) fits the 256 MB LLC, so phase C's
// re-reads of u/dt/B and ALL W traffic stay in cache; only compulsory HBM
// traffic remains (inputs once in, out once out).
template<int NCH>
__global__ __launch_bounds__(256, 4) void qssm_fused(
    const float* __restrict__ u, const float* __restrict__ dt,
    const float* __restrict__ Bin, const float* __restrict__ Cin,
    const float* __restrict__ Alog, const float* __restrict__ Ai,
    const float* __restrict__ Aj,   const float* __restrict__ Ak,
    float4* __restrict__ WQ, float4* __restrict__ WB, float* __restrict__ out)
{
    constexpr int CH  = LSEQ / NCH;   // steps per chunk
    constexpr int NDB = DQ / 128;     // d-blocks (128 d each)
    constexpr int NT  = BSZ * NCH * NDB;          // tiles for phases A/C
    constexpr int NUNITS = (BSZ * SQ) * (DQ / 16); // 256 scan units (phase B)
    constexpr int GS  = NCH / 16;     // chunks per superchunk (16 groups)

    __shared__ float4 QL[16][16];
    __shared__ float4 BL[16][16];
    __shared__ float4 HS[16][16];

    const int t = threadIdx.x;
    cg::grid_group grid = cg::this_grid();

    // ---------------- phase A: chunk summaries -> WQ/WB ----------------------
    {
        const int dl = t & 127;
        const int sh = t >> 7;          // s-half 0/1
        const int s0 = sh * 2;
        for (int tid = blockIdx.x; tid < NT; tid += gridDim.x) {
            const int dblk = tid % NDB;
            const int c    = (tid / NDB) % NCH;
            const int b    =  tid / (NDB * NCH);
            const int d    = dblk * 128 + dl;
            const int t0   = c * CH;

            HA hA0 = load_hA(Alog, Ai, Aj, Ak, d*SQ + s0);
            HA hA1 = load_hA(Alog, Ai, Aj, Ak, d*SQ + s0 + 1);

            const int base = (b*LSEQ + t0);
            const float*  dtp = dt + (size_t)base*DQ + d;
            const float4* up  = (const float4*)u   + (size_t)base*DQ + d;
            const float4* Bp  = (const float4*)Bin + (size_t)base*SQ + s0;

            PQuat Q[2], Bc[2];
            {   // peel j = 0 (summary starts at identity)
                const float a  = *dtp;
                const float aa = a * a;
                const PQuat U  = pq_of(*up);
                PQuat q, Bu;
                cayley_pk(a, aa, hA0, pq_of(Bp[0]), U, q, Bu);
                Q[0] = q; Bc[0] = Bu;
                cayley_pk(a, aa, hA1, pq_of(Bp[1]), U, q, Bu);
                Q[1] = q; Bc[1] = Bu;
                dtp += DQ; up += DQ; Bp += SQ;
            }
#pragma unroll 2
            for (int j = 1; j < CH; ++j) {
                const float a  = *dtp;
                const float aa = a * a;
                const PQuat U  = pq_of(*up);
                PQuat q, Bu;
                cayley_pk(a, aa, hA0, pq_of(Bp[0]), U, q, Bu);
                Bc[0] = pqmuladd(q, Bc[0], Bu);
                Q[0]  = pqmul(q, Q[0]);
                cayley_pk(a, aa, hA1, pq_of(Bp[1]), U, q, Bu);
                Bc[1] = pqmuladd(q, Bc[1], Bu);
                Q[1]  = pqmul(q, Q[1]);
                dtp += DQ; up += DQ; Bp += SQ;
            }
#pragma unroll
            for (int ss = 0; ss < 2; ++ss) {
                const size_t idx = ((size_t)(b*SQ + s0 + ss)*NCH + c)*DQ + d;
                WQ[idx] = f4_of(Q[ss]);
                WB[idx] = f4_of(Bc[ss]);
            }
        }
    }
    grid.sync();

    // ---------------- phase B: hierarchical scan over chunk summaries --------
    // Blocks 0..255 active; unit = (bs, 16-d group). Chunk loads batched 4-wide
    // into registers so L2/LLC latency is off the serial compose chain.
    if (blockIdx.x < NUNITS) {
        const int i  = t & 15;
        const int g  = t >> 4;                       // superchunk 0..15
        const int bs = blockIdx.x >> 5;
        const int d  = (blockIdx.x & 31) * 16 + i;
        const size_t chbase = (size_t)bs * NCH * DQ + d;

        // step 1: compose GS chunks (identity start)
        Quat Qa{1.f, 0.f, 0.f, 0.f};
        Quat Ba{0.f, 0.f, 0.f, 0.f};
        size_t idx0 = chbase + (size_t)(g * GS) * DQ;
        for (int j0 = 0; j0 < GS; j0 += 4) {
            float4 qv[4], bv[4];
#pragma unroll
            for (int j = 0; j < 4; ++j) {
                qv[j] = WQ[idx0 + (size_t)(j0 + j) * DQ];
                bv[j] = WB[idx0 + (size_t)(j0 + j) * DQ];
            }
#pragma unroll
            for (int j = 0; j < 4; ++j) {
                Ba = qmuladd(q_of(qv[j]), Ba, q_of(bv[j]));
                Qa = qmul(q_of(qv[j]), Qa);
            }
        }
        QL[g][i] = f4s_of(Qa);
        BL[g][i] = f4s_of(Ba);
        __syncthreads();

        // step 2: 16 threads scan the 16 superchunk summaries (h0 = 0)
        if (t < 16) {
            Quat h{0.f, 0.f, 0.f, 0.f};
#pragma unroll
            for (int gg = 0; gg < 16; ++gg) {
                HS[gg][t] = f4s_of(h);
                h = qmuladd(q_of(QL[gg][t]), h, q_of(BL[gg][t]));
            }
        }
        __syncthreads();

        // step 3: replay own superchunk, store h at each chunk start (in place)
        Quat h = q_of(HS[g][i]);
        for (int j0 = 0; j0 < GS; j0 += 4) {
            float4 qv[4], bv[4];
#pragma unroll
            for (int j = 0; j < 4; ++j) {
                qv[j] = WQ[idx0 + (size_t)(j0 + j) * DQ];
                bv[j] = WB[idx0 + (size_t)(j0 + j) * DQ];
            }
#pragma unroll
            for (int j = 0; j < 4; ++j) {
                WB[idx0 + (size_t)(j0 + j) * DQ] = f4s_of(h);
                h = qmuladd(q_of(qv[j]), h, q_of(bv[j]));
            }
        }
    }
    grid.sync();

    // ---------------- phase C: replay with correct h_start, emit y -----------
    {
        const int lane = t & 63;
        const int wv   = t >> 6;
        const int dl   = lane & 31;
        const int sh   = lane >> 5;
        const int s0   = sh * 2;
        for (int tid = blockIdx.x; tid < NT; tid += gridDim.x) {
            const int dblk = tid % NDB;
            const int c    = (tid / NDB) % NCH;
            const int b    =  tid / (NDB * NCH);
            const int d    = dblk * 128 + wv * 32 + dl;
            const int t0   = c * CH;

            HA hA0 = load_hA(Alog, Ai, Aj, Ak, d*SQ + s0);
            HA hA1 = load_hA(Alog, Ai, Aj, Ak, d*SQ + s0 + 1);
            PQuat h0 = pq_of(WB[((size_t)(b*SQ + s0    )*NCH + c)*DQ + d]);
            PQuat h1 = pq_of(WB[((size_t)(b*SQ + s0 + 1)*NCH + c)*DQ + d]);

            const int base = (b*LSEQ + t0);
            const float*  dtp  = dt + (size_t)base*DQ + d;
            const float4* up   = (const float4*)u   + (size_t)base*DQ + d;
            const float4* Bp   = (const float4*)Bin + (size_t)base*SQ + s0;
            const float4* Cp   = (const float4*)Cin + (size_t)base*SQ + s0;
            nfloat4*      outp = (nfloat4*)out + (size_t)base*DQ + d;

#pragma unroll 2
            for (int j = 0; j < CH; ++j) {
                const float a  = *dtp;
                const float aa = a * a;
                const PQuat U  = pq_of(*up);
                PQuat y; y.ri = mk2(0.f, 0.f); y.jk = mk2(0.f, 0.f);
                PQuat q, Bu;
                cayley_pk(a, aa, hA0, pq_of(Bp[0]), U, q, Bu);
                h0 = pqmuladd(q, h0, Bu);
                y  = pqmuladd(pq_of(Cp[0]), h0, y);
                cayley_pk(a, aa, hA1, pq_of(Bp[1]), U, q, Bu);
                h1 = pqmuladd(q, h1, Bu);
                y  = pqmuladd(pq_of(Cp[1]), h1, y);
                // reduce partial y across the two s-halves (lanes l and l^32)
                float yr = y.ri.x + __shfl_xor(y.ri.x, 32);
                float yi = y.ri.y + __shfl_xor(y.ri.y, 32);
                float yj = y.jk.x + __shfl_xor(y.jk.x, 32);
                float yk = y.jk.y + __shfl_xor(y.jk.y, 32);
                if (sh == 0) {
                    const nfloat4 yv = {yr, yi, yj, yk};
                    __builtin_nontemporal_store(yv, outp);  // out never re-read
                }
                dtp += DQ; up += DQ; Bp += SQ; Cp += SQ; outp += DQ;
            }
        }
    }
}

// ======================= fallback 3-kernel path ==============================
template<int NCH>
__global__ __launch_bounds__(256, 6) void qssm_pass1(
    const float* __restrict__ u, const float* __restrict__ dt,
    const float* __restrict__ Bin,
    const float* __restrict__ Alog, const float* __restrict__ Ai,
    const float* __restrict__ Aj,   const float* __restrict__ Ak,
    float4* __restrict__ WQ, float4* __restrict__ WB)
{
    constexpr int CH = LSEQ / NCH;
    const int t  = threadIdx.x;
    const int dl = t & 127;
    const int sh = t >> 7;
    const int d  = blockIdx.x * 128 + dl;
    const int c  = blockIdx.y;
    const int b  = blockIdx.z;
    const int s0 = sh * 2;
    const int t0 = c * CH;

    HA hA[2];
    hA[0] = load_hA(Alog, Ai, Aj, Ak, d*SQ + s0);
    hA[1] = load_hA(Alog, Ai, Aj, Ak, d*SQ + s0 + 1);

    const int base = (b*LSEQ + t0);
    const float*  dtp = dt + (size_t)base*DQ + d;
    const float4* up  = (const float4*)u   + (size_t)base*DQ + d;
    const float4* Bp  = (const float4*)Bin + (size_t)base*SQ + s0;

    PQuat Q[2], Bc[2];
    {
        const float a  = *dtp;
        const float aa = a * a;
        const PQuat U  = pq_of(*up);
#pragma unroll
        for (int ss = 0; ss < 2; ++ss) {
            PQuat q, Bu;
            cayley_pk(a, aa, hA[ss], pq_of(Bp[ss]), U, q, Bu);
            Q[ss] = q; Bc[ss] = Bu;
        }
        dtp += DQ; up += DQ; Bp += SQ;
    }
#pragma unroll 2
    for (int j = 1; j < CH; ++j) {
        const float a  = *dtp;
        const float aa = a * a;
        const PQuat U  = pq_of(*up);
#pragma unroll
        for (int ss = 0; ss < 2; ++ss) {
            PQuat q, Bu;
            cayley_pk(a, aa, hA[ss], pq_of(Bp[ss]), U, q, Bu);
            Bc[ss] = pqmuladd(q, Bc[ss], Bu);
            Q[ss]  = pqmul(q, Q[ss]);
        }
        dtp += DQ; up += DQ; Bp += SQ;
    }
#pragma unroll
    for (int ss = 0; ss < 2; ++ss) {
        const size_t idx = ((size_t)(b*SQ + s0 + ss)*NCH + c)*DQ + d;
        WQ[idx] = f4_of(Q[ss]);
        WB[idx] = f4_of(Bc[ss]);
    }
}

template<int NCH>
__global__ __launch_bounds__(512) void qssm_pass2(
    const float4* __restrict__ WQ, float4* __restrict__ WB)
{
    constexpr int GS = 8;
    constexpr int NG = NCH / GS;
    __shared__ float4 QL[NG][16];
    __shared__ float4 BL[NG][16];
    __shared__ float4 HS[NG][16];

    const int t  = threadIdx.x;
    const int i  = t & 15;
    const int g  = t >> 4;
    const int bs = blockIdx.x >> 5;
    const int d  = (blockIdx.x & 31) * 16 + i;
    const size_t chbase = (size_t)bs * NCH * DQ + d;

    size_t idx = chbase + (size_t)(g * GS) * DQ;
    Quat Qa = q_of(WQ[idx]);
    Quat Ba = q_of(WB[idx]);
#pragma unroll
    for (int j = 1; j < GS; ++j) {
        idx += DQ;
        const Quat Qc = q_of(WQ[idx]);
        const Quat Bc = q_of(WB[idx]);
        Ba = qmuladd(Qc, Ba, Bc);
        Qa = qmul(Qc, Qa);
    }
    QL[g][i] = f4s_of(Qa);
    BL[g][i] = f4s_of(Ba);
    __syncthreads();

    if (t < 16) {
        Quat h{0.f, 0.f, 0.f, 0.f};
#pragma unroll
        for (int gg = 0; gg < NG; ++gg) {
            HS[gg][t] = f4s_of(h);
            h = qmuladd(q_of(QL[gg][t]), h, q_of(BL[gg][t]));
        }
    }
    __syncthreads();

    Quat h = q_of(HS[g][i]);
    idx = chbase + (size_t)(g * GS) * DQ;
#pragma unroll
    for (int j = 0; j < GS; ++j) {
        const Quat Qc = q_of(WQ[idx]);
        const Quat Bc = q_of(WB[idx]);
        WB[idx] = f4s_of(h);
        h = qmuladd(Qc, h, Bc);
        idx += DQ;
    }
}

template<int NCH>
__global__ __launch_bounds__(256, 6) void qssm_pass3(
    const float* __restrict__ u, const float* __restrict__ dt,
    const float* __restrict__ Bin, const float* __restrict__ Cin,
    const float* __restrict__ Alog, const float* __restrict__ Ai,
    const float* __restrict__ Aj,   const float* __restrict__ Ak,
    const float4* __restrict__ WB, float* __restrict__ out)
{
    constexpr int CH = LSEQ / NCH;
    const int t    = threadIdx.x;
    const int lane = t & 63;
    const int wv   = t >> 6;
    const int dl   = lane & 31;
    const int sh   = lane >> 5;
    const int s0   = sh * 2;
    const int d = blockIdx.x * 128 + wv * 32 + dl;
    const int c = blockIdx.y;
    const int b = blockIdx.z;
    const int t0 = c * CH;

    HA hA[2];
    PQuat h[2];
#pragma unroll
    for (int ss = 0; ss < 2; ++ss) {
        hA[ss] = load_hA(Alog, Ai, Aj, Ak, d*SQ + s0 + ss);
        h[ss] = pq_of(WB[((size_t)(b*SQ + s0 + ss)*NCH + c)*DQ + d]);
    }
    const int base = (b*LSEQ + t0);
    const float*  dtp  = dt + (size_t)base*DQ + d;
    const float4* up   = (const float4*)u   + (size_t)base*DQ + d;
    const float4* Bp   = (const float4*)Bin + (size_t)base*SQ + s0;
    const float4* Cp   = (const float4*)Cin + (size_t)base*SQ + s0;
    nfloat4*      outp = (nfloat4*)out + (size_t)base*DQ + d;

#pragma unroll 2
    for (int j = 0; j < CH; ++j) {
        const float a  = *dtp;
        const float aa = a * a;
        const PQuat U  = pq_of(*up);
        PQuat y; y.ri = mk2(0.f, 0.f); y.jk = mk2(0.f, 0.f);
#pragma unroll
        for (int ss = 0; ss < 2; ++ss) {
            const PQuat Cq = pq_of(Cp[ss]);
            PQuat q, Bu;
            cayley_pk(a, aa, hA[ss], pq_of(Bp[ss]), U, q, Bu);
            h[ss] = pqmuladd(q, h[ss], Bu);
            y = pqmuladd(Cq, h[ss], y);
        }
        float yr = y.ri.x + __shfl_xor(y.ri.x, 32);
        float yi = y.ri.y + __shfl_xor(y.ri.y, 32);
        float yj = y.jk.x + __shfl_xor(y.jk.x, 32);
        float yk = y.jk.y + __shfl_xor(y.jk.y, 32);
        if (sh == 0) {
            const nfloat4 yv = {yr, yi, yj, yk};
            __builtin_nontemporal_store(yv, outp);
        }
        dtp += DQ; up += DQ; Bp += SQ; Cp += SQ; outp += DQ;
    }
}

// ======================= host launch =========================================
template<int NCH>
static void launch_all(const float* u, const float* dt, const float* Bin,
                       const float* Cin, const float* Alog, const float* Ai,
                       const float* Aj, const float* Ak,
                       float* out, void* d_ws, hipStream_t stream) {
    const size_t elems = (size_t)BSZ * SQ * NCH * DQ;
    float4* WQ = (float4*)d_ws;
    float4* WB = WQ + elems;

    // preferred: single cooperative fused kernel (2 grid syncs, LLC-resident W)
    void* kargs[] = {(void*)&u, (void*)&dt, (void*)&Bin, (void*)&Cin,
                     (void*)&Alog, (void*)&Ai, (void*)&Aj, (void*)&Ak,
                     (void*)&WQ, (void*)&WB, (void*)&out};
    hipError_t e = hipLaunchCooperativeKernel(
        reinterpret_cast<void*>(qssm_fused<NCH>),
        dim3(1024), dim3(256), kargs, 0, stream);
    if (e == hipSuccess) return;
    (void)hipGetLastError();   // clear sticky error, fall back

    dim3 g1(DQ / 128, NCH, BSZ);
    qssm_pass1<NCH><<<g1, 256, 0, stream>>>(u, dt, Bin, Alog, Ai, Aj, Ak, WQ, WB);
    qssm_pass2<NCH><<<(BSZ*SQ*DQ)/16, 16*(NCH/8), 0, stream>>>(WQ, WB);
    dim3 g3(DQ / 128, NCH, BSZ);
    qssm_pass3<NCH><<<g3, 256, 0, stream>>>(u, dt, Bin, Cin, Alog, Ai, Aj, Ak, WB, out);
}

extern "C" void kernel_launch(void* const* d_in, const int* in_sizes, int n_in,
                              void* d_out, int out_size, void* d_ws, size_t ws_size,
                              hipStream_t stream) {
    const float* u    = (const float*)d_in[0];
    const float* dt   = (const float*)d_in[1];
    const float* Bin  = (const float*)d_in[2];
    const float* Cin  = (const float*)d_in[3];
    const float* Alog = (const float*)d_in[4];
    const float* Ai   = (const float*)d_in[5];
    const float* Aj   = (const float*)d_in[6];
    const float* Ak   = (const float*)d_in[7];
    float* out = (float*)d_out;

    auto ws_need = [](int nch) -> size_t {
        return 2ull * BSZ * SQ * (size_t)nch * DQ * sizeof(float4);
    };
    if (ws_size >= ws_need(256)) {
        launch_all<256>(u, dt, Bin, Cin, Alog, Ai, Aj, Ak, out, d_ws, stream);
    } else if (ws_size >= ws_need(128)) {
        launch_all<128>(u, dt, Bin, Cin, Alog, Ai, Aj, Ak, out, d_ws, stream);
    } else {
        launch_all<64>(u, dt, Bin, Cin, Alog, Ai, Aj, Ak, out, d_ws, stream);
    }
}

// Round 3
// 151.681 us; speedup vs baseline: 2.6876x; 2.6876x over previous
//
#include <hip/hip_runtime.h>

#define BSZ   2
#define LSEQ  2048
#define DQ    512
#define SQ    4
#define EPSQ  1e-6f

typedef float nfloat4 __attribute__((ext_vector_type(4)));  // native vec for nontemporal
typedef float nfloat2 __attribute__((ext_vector_type(2)));  // VOP3P packed pair

__device__ __forceinline__ nfloat2 mk2(float x, float y) { nfloat2 v; v.x = x; v.y = y; return v; }

// ---------------- packed quaternion (pairs (r,i),(j,k); v_pk_fma_f32 path) ---
struct PQuat { nfloat2 ri, jk; };

__device__ __forceinline__ PQuat pq_of(const float4 v) {
    PQuat p; p.ri = mk2(v.x, v.y); p.jk = mk2(v.z, v.w); return p;
}
__device__ __forceinline__ float4 f4_of(const PQuat p) {
    return make_float4(p.ri.x, p.ri.y, p.jk.x, p.jk.y);
}

// o = a x b  (8 packed mul/fma vs 16 scalar)
__device__ __forceinline__ PQuat pqmul(const PQuat a, const PQuat b) {
    const float ar = a.ri.x, ai = a.ri.y, aj = a.jk.x, ak = a.jk.y;
    PQuat o;
    o.ri = ar*b.ri + ai*mk2(-b.ri.y,  b.ri.x)
         + aj*mk2(-b.jk.x,  b.jk.y) + ak*mk2(-b.jk.y, -b.jk.x);
    o.jk = ar*b.jk + ai*mk2(-b.jk.y,  b.jk.x)
         + aj*mk2( b.ri.x, -b.ri.y) + ak*mk2( b.ri.y,  b.ri.x);
    return o;
}

// o = a x b + c
__device__ __forceinline__ PQuat pqmuladd(const PQuat a, const PQuat b, const PQuat c) {
    const float ar = a.ri.x, ai = a.ri.y, aj = a.jk.x, ak = a.jk.y;
    PQuat o;
    o.ri = c.ri + ar*b.ri + ai*mk2(-b.ri.y,  b.ri.x)
         + aj*mk2(-b.jk.x,  b.jk.y) + ak*mk2(-b.jk.y, -b.jk.x);
    o.jk = c.jk + ar*b.jk + ai*mk2(-b.jk.y,  b.jk.x)
         + aj*mk2( b.ri.x, -b.ri.y) + ak*mk2( b.ri.y,  b.ri.x);
    return o;
}

// Precomputed per-(d,s) A-quaternion state (hA = 0.5*dt-free part).
struct HA { float r, i; nfloat2 jk; float p2, n2r; };

__device__ __forceinline__ HA load_hA(const float* __restrict__ Alog,
                                      const float* __restrict__ Ai,
                                      const float* __restrict__ Aj,
                                      const float* __restrict__ Ak, int idx) {
    HA h;
    h.r  = -0.5f * __expf(Alog[idx]);
    h.i  =  0.5f * Ai[idx];
    h.jk = mk2(0.5f * Aj[idx], 0.5f * Ak[idx]);
    h.p2 = h.r*h.r + h.i*h.i + h.jk.x*h.jk.x + h.jk.y*h.jk.y;
    h.n2r = -2.0f * h.r;
    return h;
}

// Cayley transition q and injection Bu (packed, strength-reduced).
__device__ __forceinline__ void cayley_pk(const float a, const float aa, const HA& hA,
                                          const PQuat B, const PQuat U,
                                          PQuat& q, PQuat& Bu) {
    const float dd = __builtin_fmaf(aa, hA.p2, __builtin_fmaf(a, hA.n2r, 1.0f + EPSQ));
    const float sv = __builtin_amdgcn_rcpf(dd);
    const float nr = __builtin_fmaf(-aa, hA.p2, 1.0f);   // 1 - |w|^2
    const float as = a * sv;
    const float s2a = as + as;                            // 2*a*s
    q.ri = mk2(nr * sv, s2a * hA.i);
    q.jk = s2a * hA.jk;
    PQuat cd;                                             // conj(den) = (1-wr, w_im)
    cd.ri = mk2(__builtin_fmaf(-a, hA.r, 1.0f), a * hA.i);
    cd.jk = a * hA.jk;
    const PQuat cb = pqmul(cd, B);
    PQuat dB; dB.ri = as * cb.ri; dB.jk = as * cb.jk;
    Bu = pqmul(dB, U);
}

// ---------------- scalar quat (pass2 only) -----------------------------------
struct Quat { float r, i, j, k; };
__device__ __forceinline__ Quat qmul(const Quat a, const Quat b) {
    Quat o;
    o.r = a.r*b.r - a.i*b.i - a.j*b.j - a.k*b.k;
    o.i = a.r*b.i + a.i*b.r + a.j*b.k - a.k*b.j;
    o.j = a.r*b.j - a.i*b.k + a.j*b.r + a.k*b.i;
    o.k = a.r*b.k + a.i*b.j - a.j*b.i + a.k*b.r;
    return o;
}
__device__ __forceinline__ Quat qmuladd(const Quat a, const Quat b, const Quat c) {
    Quat o;
    o.r = c.r + a.r*b.r - a.i*b.i - a.j*b.j - a.k*b.k;
    o.i = c.i + a.r*b.i + a.i*b.r + a.j*b.k - a.k*b.j;
    o.j = c.j + a.r*b.j - a.i*b.k + a.j*b.r + a.k*b.i;
    o.k = c.k + a.r*b.k + a.i*b.j - a.j*b.i + a.k*b.r;
    return o;
}
__device__ __forceinline__ Quat q_of(const float4 v) { return Quat{v.x, v.y, v.z, v.w}; }
__device__ __forceinline__ float4 f4s_of(const Quat q) { return make_float4(q.r, q.i, q.j, q.k); }

// ---------------- async global->LDS staging helpers --------------------------
// HW contract (m03/m97/m104): LDS dest = wave-uniform base + lane*size;
// global src is per-lane. size literal 16 or 4.
typedef unsigned int u32_t;
__device__ __forceinline__ void gl_lds16(const void* g, void* l) {
    __builtin_amdgcn_global_load_lds(
        (const __attribute__((address_space(1))) u32_t*)g,
        (__attribute__((address_space(3))) u32_t*)l, 16, 0, 0);
}
__device__ __forceinline__ void gl_lds4(const void* g, void* l) {
    __builtin_amdgcn_global_load_lds(
        (const __attribute__((address_space(1))) u32_t*)g,
        (__attribute__((address_space(3))) u32_t*)l, 4, 0, 0);
}

// ---------------- pass 1: chunk summaries, LDS-staged ------------------------
// grid: (DQ/128, NCH, BSZ), block 256 (4 waves). Whole chunk (u 16K, dt 4K,
// B 0.5K = 20.5 KB) staged async into LDS in one burst -> ~125 KB in flight
// per CU at 6 resident blocks; compute then reads LDS (both s-halves share u).
template<int NCH>
__global__ __launch_bounds__(256, 6) void qssm_pass1(
    const float* __restrict__ u, const float* __restrict__ dt,
    const float* __restrict__ Bin,
    const float* __restrict__ Alog, const float* __restrict__ Ai,
    const float* __restrict__ Aj,   const float* __restrict__ Ak,
    float4* __restrict__ WQ, float4* __restrict__ WB)
{
    constexpr int CH = LSEQ / NCH;     // 8 steps per chunk
    __shared__ float4 uL[CH][128];
    __shared__ float  dtL[CH][128];
    __shared__ float4 BL[CH][SQ];

    const int t    = threadIdx.x;
    const int lane = t & 63;
    const int wid  = t >> 6;
    const int dblk = blockIdx.x;
    const int c    = blockIdx.y;
    const int b    = blockIdx.z;
    const int t0   = c * CH;
    const int base = b*LSEQ + t0;

    // ---- stage chunk (async, no VGPR round-trip) ----
    const float4* ug  = (const float4*)u + (size_t)base*DQ + dblk*128;
    const float*  dtg = dt + (size_t)base*DQ + dblk*128;
    const float*  Bg  = Bin + (size_t)base*SQ*4;   // CH*SQ*4 = 128 floats contiguous
#pragma unroll
    for (int jj = 0; jj < CH/4; ++jj) {            // 4 waves x 2 rows each
        const int j = wid*(CH/4) + jj;
#pragma unroll
        for (int k = 0; k < 2; ++k) {
            gl_lds16(ug  + (size_t)j*DQ + k*64 + lane, &uL[j][k*64]);
            gl_lds4 (dtg + (size_t)j*DQ + k*64 + lane, &dtL[j][k*64]);
        }
    }
    if (wid == 0) {
#pragma unroll
        for (int k = 0; k < 2; ++k)
            gl_lds4(Bg + k*64 + lane, ((float*)BL) + k*64);
    }

    const int dl = t & 127;
    const int sh = t >> 7;            // s-half 0/1
    const int s0 = sh * 2;
    const int d  = dblk*128 + dl;

    HA hA0 = load_hA(Alog, Ai, Aj, Ak, d*SQ + s0);
    HA hA1 = load_hA(Alog, Ai, Aj, Ak, d*SQ + s0 + 1);

    __syncthreads();                  // drains vmcnt incl. global_load_lds

    PQuat Q[2], Bc[2];
    {   // peel j = 0 (summary starts at identity)
        const float a  = dtL[0][dl];
        const float aa = a * a;
        const PQuat U  = pq_of(uL[0][dl]);
        PQuat q, Bu;
        cayley_pk(a, aa, hA0, pq_of(BL[0][s0]),     U, q, Bu);
        Q[0] = q; Bc[0] = Bu;
        cayley_pk(a, aa, hA1, pq_of(BL[0][s0 + 1]), U, q, Bu);
        Q[1] = q; Bc[1] = Bu;
    }
#pragma unroll
    for (int j = 1; j < CH; ++j) {
        const float a  = dtL[j][dl];
        const float aa = a * a;
        const PQuat U  = pq_of(uL[j][dl]);
        PQuat q, Bu;
        cayley_pk(a, aa, hA0, pq_of(BL[j][s0]),     U, q, Bu);
        Bc[0] = pqmuladd(q, Bc[0], Bu);
        Q[0]  = pqmul(q, Q[0]);
        cayley_pk(a, aa, hA1, pq_of(BL[j][s0 + 1]), U, q, Bu);
        Bc[1] = pqmuladd(q, Bc[1], Bu);
        Q[1]  = pqmul(q, Q[1]);
    }
#pragma unroll
    for (int ss = 0; ss < 2; ++ss) {
        const size_t idx = ((size_t)(b*SQ + s0 + ss)*NCH + c)*DQ + d;
        WQ[idx] = f4_of(Q[ss]);
        WB[idx] = f4_of(Bc[ss]);
    }
}

// ---------------- pass 2: hierarchical scan (round-1 version, proven) --------
template<int NCH>
__global__ __launch_bounds__(512) void qssm_pass2(
    const float4* __restrict__ WQ, float4* __restrict__ WB)
{
    constexpr int GS = 8;           // chunks per superchunk
    constexpr int NG = NCH / GS;    // superchunks per channel
    __shared__ float4 QL[NG][16];
    __shared__ float4 BL2[NG][16];
    __shared__ float4 HS[NG][16];

    const int t  = threadIdx.x;
    const int i  = t & 15;
    const int g  = t >> 4;
    const int bs = blockIdx.x >> 5;
    const int d  = (blockIdx.x & 31) * 16 + i;
    const size_t chbase = (size_t)bs * NCH * DQ + d;

    size_t idx = chbase + (size_t)(g * GS) * DQ;
    Quat Qa = q_of(WQ[idx]);
    Quat Ba = q_of(WB[idx]);
#pragma unroll
    for (int j = 1; j < GS; ++j) {
        idx += DQ;
        const Quat Qc = q_of(WQ[idx]);
        const Quat Bc = q_of(WB[idx]);
        Ba = qmuladd(Qc, Ba, Bc);
        Qa = qmul(Qc, Qa);
    }
    QL[g][i]  = f4s_of(Qa);
    BL2[g][i] = f4s_of(Ba);
    __syncthreads();

    if (t < 16) {
        Quat h{0.f, 0.f, 0.f, 0.f};
#pragma unroll
        for (int gg = 0; gg < NG; ++gg) {
            HS[gg][t] = f4s_of(h);
            h = qmuladd(q_of(QL[gg][t]), h, q_of(BL2[gg][t]));
        }
    }
    __syncthreads();

    Quat h = q_of(HS[g][i]);
    idx = chbase + (size_t)(g * GS) * DQ;
#pragma unroll
    for (int j = 0; j < GS; ++j) {
        const Quat Qc = q_of(WQ[idx]);
        const Quat Bc = q_of(WB[idx]);
        WB[idx] = f4s_of(h);
        h = qmuladd(Qc, h, Bc);
        idx += DQ;
    }
}

// ---------------- pass 3: replay with correct h_start, LDS-staged ------------
// grid: (DQ/128, NCH, BSZ), block 256 = 4 waves. Wave: 32 d x 2 s-halves
// (lane = 32*sh + dl); y reduced via shfl_xor(32); sh==0 lanes store.
template<int NCH>
__global__ __launch_bounds__(256, 6) void qssm_pass3(
    const float* __restrict__ u, const float* __restrict__ dt,
    const float* __restrict__ Bin, const float* __restrict__ Cin,
    const float* __restrict__ Alog, const float* __restrict__ Ai,
    const float* __restrict__ Aj,   const float* __restrict__ Ak,
    const float4* __restrict__ WB, float* __restrict__ out)
{
    constexpr int CH = LSEQ / NCH;
    __shared__ float4 uL[CH][128];
    __shared__ float  dtL[CH][128];
    __shared__ float4 BL[CH][SQ];
    __shared__ float4 CL[CH][SQ];

    const int t    = threadIdx.x;
    const int lane = t & 63;
    const int wid  = t >> 6;
    const int dblk = blockIdx.x;
    const int c    = blockIdx.y;
    const int b    = blockIdx.z;
    const int t0   = c * CH;
    const int base = b*LSEQ + t0;

    // ---- stage chunk ----
    const float4* ug  = (const float4*)u + (size_t)base*DQ + dblk*128;
    const float*  dtg = dt + (size_t)base*DQ + dblk*128;
    const float*  Bg  = Bin + (size_t)base*SQ*4;
    const float*  Cg  = Cin + (size_t)base*SQ*4;
#pragma unroll
    for (int jj = 0; jj < CH/4; ++jj) {
        const int j = wid*(CH/4) + jj;
#pragma unroll
        for (int k = 0; k < 2; ++k) {
            gl_lds16(ug  + (size_t)j*DQ + k*64 + lane, &uL[j][k*64]);
            gl_lds4 (dtg + (size_t)j*DQ + k*64 + lane, &dtL[j][k*64]);
        }
    }
    if (wid == 0) {
#pragma unroll
        for (int k = 0; k < 2; ++k)
            gl_lds4(Bg + k*64 + lane, ((float*)BL) + k*64);
    } else if (wid == 1) {
#pragma unroll
        for (int k = 0; k < 2; ++k)
            gl_lds4(Cg + k*64 + lane, ((float*)CL) + k*64);
    }

    const int dl = lane & 31;
    const int sh = lane >> 5;
    const int s0 = sh * 2;
    const int dloc = wid*32 + dl;          // within-block d offset 0..127
    const int d    = dblk*128 + dloc;

    HA hA0 = load_hA(Alog, Ai, Aj, Ak, d*SQ + s0);
    HA hA1 = load_hA(Alog, Ai, Aj, Ak, d*SQ + s0 + 1);
    PQuat h0 = pq_of(WB[((size_t)(b*SQ + s0    )*NCH + c)*DQ + d]);
    PQuat h1 = pq_of(WB[((size_t)(b*SQ + s0 + 1)*NCH + c)*DQ + d]);

    nfloat4* outp = (nfloat4*)out + (size_t)base*DQ + d;

    __syncthreads();

#pragma unroll
    for (int j = 0; j < CH; ++j) {
        const float a  = dtL[j][dloc];
        const float aa = a * a;
        const PQuat U  = pq_of(uL[j][dloc]);
        PQuat y; y.ri = mk2(0.f, 0.f); y.jk = mk2(0.f, 0.f);
        PQuat q, Bu;
        cayley_pk(a, aa, hA0, pq_of(BL[j][s0]),     U, q, Bu);
        h0 = pqmuladd(q, h0, Bu);
        y  = pqmuladd(pq_of(CL[j][s0]),     h0, y);
        cayley_pk(a, aa, hA1, pq_of(BL[j][s0 + 1]), U, q, Bu);
        h1 = pqmuladd(q, h1, Bu);
        y  = pqmuladd(pq_of(CL[j][s0 + 1]), h1, y);
        // reduce partial y across the two s-halves (lanes l and l^32)
        float yr = y.ri.x + __shfl_xor(y.ri.x, 32);
        float yi = y.ri.y + __shfl_xor(y.ri.y, 32);
        float yj = y.jk.x + __shfl_xor(y.jk.x, 32);
        float yk = y.jk.y + __shfl_xor(y.jk.y, 32);
        if (sh == 0) {
            const nfloat4 yv = {yr, yi, yj, yk};
            __builtin_nontemporal_store(yv, outp);  // out never re-read
        }
        outp += DQ;
    }
}

// ======================= host launch =========================================
template<int NCH>
static void launch_all(const float* u, const float* dt, const float* Bin,
                       const float* Cin, const float* Alog, const float* Ai,
                       const float* Aj, const float* Ak,
                       float* out, void* d_ws, hipStream_t stream) {
    const size_t elems = (size_t)BSZ * SQ * NCH * DQ;
    float4* WQ = (float4*)d_ws;
    float4* WB = WQ + elems;
    dim3 g1(DQ / 128, NCH, BSZ);
    qssm_pass1<NCH><<<g1, 256, 0, stream>>>(u, dt, Bin, Alog, Ai, Aj, Ak, WQ, WB);
    qssm_pass2<NCH><<<(BSZ*SQ*DQ)/16, 16*(NCH/8), 0, stream>>>(WQ, WB);
    dim3 g3(DQ / 128, NCH, BSZ);
    qssm_pass3<NCH><<<g3, 256, 0, stream>>>(u, dt, Bin, Cin, Alog, Ai, Aj, Ak, WB, out);
}

extern "C" void kernel_launch(void* const* d_in, const int* in_sizes, int n_in,
                              void* d_out, int out_size, void* d_ws, size_t ws_size,
                              hipStream_t stream) {
    const float* u    = (const float*)d_in[0];
    const float* dt   = (const float*)d_in[1];
    const float* Bin  = (const float*)d_in[2];
    const float* Cin  = (const float*)d_in[3];
    const float* Alog = (const float*)d_in[4];
    const float* Ai   = (const float*)d_in[5];
    const float* Aj   = (const float*)d_in[6];
    const float* Ak   = (const float*)d_in[7];
    float* out = (float*)d_out;

    auto ws_need = [](int nch) -> size_t {
        return 2ull * BSZ * SQ * (size_t)nch * DQ * sizeof(float4);
    };
    if (ws_size >= ws_need(256)) {
        launch_all<256>(u, dt, Bin, Cin, Alog, Ai, Aj, Ak, out, d_ws, stream);
    } else if (ws_size >= ws_need(128)) {
        launch_all<128>(u, dt, Bin, Cin, Alog, Ai, Aj, Ak, out, d_ws, stream);
    } else {
        launch_all<64>(u, dt, Bin, Cin, Alog, Ai, Aj, Ak, out, d_ws, stream);
    }
}